// Round 2
// baseline (552.313 us; speedup 1.0000x reference)
//
#include <hip/hip_runtime.h>

#define HW_IMG (224*224)
#define SCALE 0.17677669529663687f   // 1/sqrt(32)

// ---- prep1: qh[r] = in_b[r] + query . in_w[r,:]; cb[r] = out_b[r] + out_w[r,:] . aob ----
__global__ void prep1_kernel(const float* __restrict__ query,
                             const float* __restrict__ in_w,
                             const float* __restrict__ in_b,
                             const float* __restrict__ out_w,
                             const float* __restrict__ aob,
                             const float* __restrict__ out_b,
                             float* __restrict__ qh,
                             float* __restrict__ cb) {
  const int r = blockIdx.x, tid = threadIdx.x;
  float p1 = query[tid] * in_w[r*256 + tid];
  float p2 = aob[tid]   * out_w[r*256 + tid];
  #pragma unroll
  for (int o = 32; o; o >>= 1) { p1 += __shfl_xor(p1, o); p2 += __shfl_xor(p2, o); }
  __shared__ float t1[4], t2[4];
  if ((tid & 63) == 0) { t1[tid>>6] = p1; t2[tid>>6] = p2; }
  __syncthreads();
  if (tid == 0) qh[r] = in_b[r] + t1[0]+t1[1]+t1[2]+t1[3];
  if (tid == 1) cb[r] = out_b[r] + t2[0]+t2[1]+t2[2]+t2[3];
}

// ---- prep2: qk_t[c][h] = SCALE * sum_d qh[h*32+d] * wk[h*32+d][c] ----
__global__ void prep2_kernel(const float* __restrict__ qh,
                             const float* __restrict__ in_w,
                             float* __restrict__ qk_t) {
  const int h = blockIdx.x, c = threadIdx.x;
  float s = 0.f;
  #pragma unroll
  for (int d = 0; d < 32; ++d)
    s += qh[h*32 + d] * in_w[(256 + h*32 + d)*256 + c];
  qk_t[c*8 + h] = s * SCALE;
}

// ---- prep3: wvT and (out_w @ attn_out_w)^T ----
__global__ void prep3_kernel(const float* __restrict__ in_w,
                             const float* __restrict__ aw,
                             const float* __restrict__ out_w,
                             float* __restrict__ wvT,
                             float* __restrict__ cwT) {
  const int o = blockIdx.x, t = threadIdx.x;
  wvT[t*256 + o] = in_w[(512 + o)*256 + t];
  float a = 0.f;
  #pragma unroll 4
  for (int k = 0; k < 256; ++k) a += out_w[o*256 + k] * aw[k*256 + t];
  cwT[t*256 + o] = a;
}

// ---- main: one block per patch, single pass over X (online softmax over l-tiles of 28) ----
__global__ __launch_bounds__(256, 4) void attnpool_main(
    const float* __restrict__ X,
    const float* __restrict__ in_b,
    const float* __restrict__ qk_t,
    const float* __restrict__ wvT,
    const float* __restrict__ cwT,
    const float* __restrict__ cb,
    float* __restrict__ out) {
  __shared__ float Xs[28*256];   // swizzled: word(l,c) = l*256 + (((c>>2)^(l&7))<<2) + (c&3)
  __shared__ float QK[8*256];    // [h][c]
  __shared__ float Wt[28*8];     // tile attn weights [l][h] (unnormalized)
  __shared__ float SCs[8];       // per-tile rescale per head
  __shared__ float DFs[8];       // running denominator per head

  const int tid = threadIdx.x;
  const int bid = blockIdx.x;
  const int n = (bid & 7) * 256 + (bid >> 3);   // XCD swizzle (2048 % 8 == 0, bijective)
  const int b = n >> 8, rem = n & 255, pi = rem >> 4, pj = rem & 15;
  const float* __restrict__ xb = X + (size_t)b*256*HW_IMG + pi*14*224 + pj*14;

  // stage qk into LDS [h][c]
  {
    const float4 qa = ((const float4*)qk_t)[2*tid];
    const float4 qb = ((const float4*)qk_t)[2*tid + 1];
    QK[0*256+tid]=qa.x; QK[1*256+tid]=qa.y; QK[2*256+tid]=qa.z; QK[3*256+tid]=qa.w;
    QK[4*256+tid]=qb.x; QK[5*256+tid]=qb.y; QK[6*256+tid]=qb.z; QK[7*256+tid]=qb.w;
  }

  // per-thread load mapping (tile-invariant): 14 float2 per thread per tile
  int goff[14];   // global offset (floats) relative to xb + t*448
  int wob[14];    // LDS byte offset for v.x (v.y at (wob+1024)^16)
  #pragma unroll
  for (int it = 0; it < 14; ++it) {
    const int e = it*256 + tid;
    const int c = e / 14;
    const int p = e - c*14;
    const int r = 2*p;                       // tile row (even), v.y -> r+1
    goff[it] = c*HW_IMG + (r/14)*224 + (r - (r/14)*14);
    wob[it]  = (r*256 + (((c>>2) ^ (r&7))<<2) + (c&3)) * 4;
  }

  float2 v[14];
  #pragma unroll
  for (int it = 0; it < 14; ++it) v[it] = *(const float2*)(xb + goff[it]);

  float m = -INFINITY, d = 0.f;
  float4 accA = {0,0,0,0}, accB = {0,0,0,0};

  // score-phase mapping
  const int g  = tid >> 5;                  // head
  const int l  = tid & 31;                  // tile row (active l<28)
  const int la = (l < 28) ? l : 27;
  const int K  = la & 7;
  int qko[8];
  #pragma unroll
  for (int j = 0; j < 8; ++j) qko[j] = g*1024 + ((j ^ K) << 4);

  // pooling-phase mapping
  const int hp = tid >> 6;                  // head pair (2hp, 2hp+1)
  const int lq = tid & 63;                  // channel quad
  int po[8];
  #pragma unroll
  for (int k = 0; k < 8; ++k) po[k] = (lq ^ k) << 4;

  #pragma unroll 1
  for (int t = 0; t < 7; ++t) {
    __syncthreads();                        // previous tile fully consumed
    #pragma unroll
    for (int it = 0; it < 14; ++it) {
      *(float*)((char*)Xs + wob[it]) = v[it].x;
      *(float*)((char*)Xs + ((wob[it] + 1024) ^ 16)) = v[it].y;
    }
    if (t != 6) {
      const float* xt = xb + (t+1)*448;
      #pragma unroll
      for (int it = 0; it < 14; ++it) v[it] = *(const float2*)(xt + goff[it]);
    }
    __syncthreads();                        // Xs (and QK on t=0) visible

    // ---- scores: s[l][g] = sum_c Xs[l][c] * QK[g][c], XOR folded into iteration order ----
    float s;
    {
      float acc = 0.f;
      const char* xrow = (const char*)Xs + la*1024;
      const char* qkc  = (const char*)QK;
      #pragma unroll
      for (int pq = 0; pq < 64; ++pq) {
        const float4 xv = *(const float4*)(xrow + pq*16);
        const float4 qv = *(const float4*)(qkc + qko[pq & 7] + (pq >> 3)*128);
        acc += xv.x*qv.x + xv.y*qv.y + xv.z*qv.z + xv.w*qv.w;
      }
      s = (l < 28) ? acc : -INFINITY;
    }

    // ---- online softmax per head (group of 32 lanes) ----
    float tmax = s;
    #pragma unroll
    for (int o = 16; o; o >>= 1) tmax = fmaxf(tmax, __shfl_xor(tmax, o, 32));
    const float nm  = fmaxf(m, tmax);
    const float al  = __expf(s - nm);       // 0 for inactive lanes
    float ts = al;
    #pragma unroll
    for (int o = 16; o; o >>= 1) ts += __shfl_xor(ts, o, 32);
    const float scl = __expf(m - nm);
    d = d*scl + ts;
    m = nm;
    if (l < 28) Wt[l*8 + g] = al;
    if (l == 0) { SCs[g] = scl; DFs[g] = d; }
    __syncthreads();                        // Wt/SCs visible

    // ---- pooling: pooled[h][c] += sum_l Wt[l][h] * Xs[l][c] ----
    {
      const float2 s2 = *(const float2*)&SCs[2*hp];
      accA.x*=s2.x; accA.y*=s2.x; accA.z*=s2.x; accA.w*=s2.x;
      accB.x*=s2.y; accB.y*=s2.y; accB.z*=s2.y; accB.w*=s2.y;
      #pragma unroll
      for (int r = 0; r < 28; ++r) {
        const float2 w2 = *(const float2*)&Wt[r*8 + 2*hp];
        const float4 x4 = *(const float4*)((const char*)Xs + po[r & 7] + r*1024);
        accA.x += w2.x*x4.x; accA.y += w2.x*x4.y; accA.z += w2.x*x4.z; accA.w += w2.x*x4.w;
        accB.x += w2.y*x4.x; accB.y += w2.y*x4.y; accB.z += w2.y*x4.z; accB.w += w2.y*x4.w;
      }
    }
  }

  __syncthreads();                          // all pooling reads of Xs done
  // P = pooled / d  -> overlay on Xs[0..2047]
  {
    const float2 df = *(const float2*)&DFs[2*hp];
    const float ia = 1.f/df.x, ib = 1.f/df.y;
    *(float4*)&Xs[(2*hp)*256 + lq*4]   = make_float4(accA.x*ia, accA.y*ia, accA.z*ia, accA.w*ia);
    *(float4*)&Xs[(2*hp+1)*256 + lq*4] = make_float4(accB.x*ib, accB.y*ib, accB.z*ib, accB.w*ib);
  }
  __syncthreads();
  // ctx[c'] = bv[c'] + sum_c wvT[c][c'] * P[h(c')][c]
  {
    const int h2 = tid >> 5;
    float a = in_b[512 + tid];
    #pragma unroll 8
    for (int c = 0; c < 256; ++c) a += wvT[c*256 + tid] * Xs[h2*256 + c];
    Xs[2048 + tid] = a;
  }
  __syncthreads();
  // out[o] = cb[o] + sum_k cwT[k][o] * ctx[k]
  {
    float o = cb[tid];
    #pragma unroll 8
    for (int k = 0; k < 256; ++k) o += cwT[k*256 + tid] * Xs[2048 + k];
    out[(((size_t)b*256 + tid)*16 + pi)*16 + pj] = o;
  }
}

extern "C" void kernel_launch(void* const* d_in, const int* in_sizes, int n_in,
                              void* d_out, int out_size, void* d_ws, size_t ws_size,
                              hipStream_t stream) {
  const float* X    = (const float*)d_in[0];
  const float* q    = (const float*)d_in[1];
  const float* in_w = (const float*)d_in[2];
  const float* in_b = (const float*)d_in[3];
  const float* aw   = (const float*)d_in[4];
  const float* aob  = (const float*)d_in[5];
  const float* ow   = (const float*)d_in[6];
  const float* ob   = (const float*)d_in[7];
  float* out = (float*)d_out;

  float* wsf  = (float*)d_ws;
  float* qk_t = wsf;                 // 2048
  float* cb   = wsf + 2048;          // 256
  float* qh   = wsf + 2048 + 256;    // 256
  float* wvT  = wsf + 4096;          // 65536
  float* cwT  = wsf + 4096 + 65536;  // 65536

  hipLaunchKernelGGL(prep1_kernel, dim3(256),  dim3(256), 0, stream,
                     q, in_w, in_b, ow, aob, ob, qh, cb);
  hipLaunchKernelGGL(prep2_kernel, dim3(8),    dim3(256), 0, stream,
                     qh, in_w, qk_t);
  hipLaunchKernelGGL(prep3_kernel, dim3(256),  dim3(256), 0, stream,
                     in_w, aw, ow, wvT, cwT);
  hipLaunchKernelGGL(attnpool_main, dim3(2048), dim3(256), 0, stream,
                     X, in_b, qk_t, wvT, cwT, cb, out);
}

// Round 3
// 417.147 us; speedup vs baseline: 1.3240x; 1.3240x over previous
//
#include <hip/hip_runtime.h>

#define HW_IMG (224*224)
#define SCALE 0.17677669529663687f   // 1/sqrt(32)

typedef short bf16x8 __attribute__((ext_vector_type(8)));
typedef float f32x4 __attribute__((ext_vector_type(4)));
union U4B8 { uint4 u; bf16x8 b; };

__device__ __forceinline__ unsigned bf16rn(float f) {
  unsigned u = __float_as_uint(f);
  return (u + 0x7fffu + ((u >> 16) & 1u)) >> 16;
}

// ---- prep1: qh[r] = in_b[r] + query.in_w[r,:]; cb[r] = out_b[r] + out_w[r,:].aob ----
__global__ void prep1_kernel(const float* __restrict__ query,
                             const float* __restrict__ in_w,
                             const float* __restrict__ in_b,
                             const float* __restrict__ out_w,
                             const float* __restrict__ aob,
                             const float* __restrict__ out_b,
                             float* __restrict__ qh,
                             float* __restrict__ cb) {
  const int r = blockIdx.x, tid = threadIdx.x;
  float p1 = query[tid] * in_w[r*256 + tid];
  float p2 = aob[tid]   * out_w[r*256 + tid];
  #pragma unroll
  for (int o = 32; o; o >>= 1) { p1 += __shfl_xor(p1, o); p2 += __shfl_xor(p2, o); }
  __shared__ float t1[4], t2[4];
  if ((tid & 63) == 0) { t1[tid>>6] = p1; t2[tid>>6] = p2; }
  __syncthreads();
  if (tid == 0) qh[r] = in_b[r] + t1[0]+t1[1]+t1[2]+t1[3];
  if (tid == 1) cb[r] = out_b[r] + t2[0]+t2[1]+t2[2]+t2[3];
}

// ---- prep2: qk bf16 B-fragments for mfma_f32_16x16x32_bf16 ----
// frag[k][lane]: 8 bf16 = qk[c = 32k + (lane>>4)*8 + j][h = lane&15], h>=8 -> 0
__global__ void prep2_kernel(const float* __restrict__ qh,
                             const float* __restrict__ in_w,
                             unsigned short* __restrict__ qkf) {
  const int k = blockIdx.x;     // 0..7
  const int L = threadIdx.x;    // 0..63
  const int h = L & 15, q = L >> 4;
  unsigned short o[8];
  #pragma unroll
  for (int j = 0; j < 8; ++j) {
    float s = 0.f;
    if (h < 8) {
      const int c = k*32 + q*8 + j;
      #pragma unroll
      for (int dd = 0; dd < 32; ++dd)
        s += qh[h*32 + dd] * in_w[(256 + h*32 + dd)*256 + c];
      s *= SCALE;
    }
    o[j] = (unsigned short)bf16rn(s);
  }
  ushort4* dst = (ushort4*)(qkf + (size_t)(k*64 + L)*8);
  dst[0] = make_ushort4(o[0],o[1],o[2],o[3]);
  dst[1] = make_ushort4(o[4],o[5],o[6],o[7]);
}

// ---- prep3: wvT and (out_w @ attn_out_w)^T ----
__global__ void prep3_kernel(const float* __restrict__ in_w,
                             const float* __restrict__ aw,
                             const float* __restrict__ out_w,
                             float* __restrict__ wvT,
                             float* __restrict__ cwT) {
  const int o = blockIdx.x, t = threadIdx.x;
  wvT[t*256 + o] = in_w[(512 + o)*256 + t];
  float a = 0.f;
  #pragma unroll 4
  for (int k = 0; k < 256; ++k) a += out_w[o*256 + k] * aw[k*256 + t];
  cwT[t*256 + o] = a;
}

// ---- main: one block per patch; bf16 LDS tile; MFMA scores; VALU pooling ----
__global__ __launch_bounds__(256, 4) void attnpool_main(
    const float* __restrict__ X,
    const float* __restrict__ in_b,
    const unsigned short* __restrict__ qkf,
    const float* __restrict__ wvT,
    const float* __restrict__ cwT,
    const float* __restrict__ cb,
    float* __restrict__ out) {
  // bf16 tile: element (r, c) -> u32 word r*160 + (c>>1) + 4*((r>>1)&7), lo=even c
  __shared__ float Xs[32*160];        // 20.5 KB (rows 28..31 zeroed pad)
  __shared__ float Wl[28*8];          // attn weights (unnormalized alpha) [l][h]
  __shared__ float Ms[32], Ss[32];    // per-wave max / sum staging [wid][hcol]
  __shared__ float SCs[8], Ds[8];     // per-tile rescale / final denom per head

  const int tid = threadIdx.x;
  const int wid = tid >> 6;
  const int lane = tid & 63;
  const int bid = blockIdx.x;
  const int n = (bid & 7) * 256 + (bid >> 3);   // XCD swizzle (2048%8==0)
  const int b = n >> 8, rem = n & 255, pi = rem >> 4, pj = rem & 15;
  const float* __restrict__ xb = X + (size_t)b*256*HW_IMG + pi*14*224 + pj*14;

  for (int z = tid; z < 640; z += 256) Xs[28*160 + z] = 0.f;  // zero pad rows

  // qk B-fragments (registers, all ksteps)
  uint4 qkg[8];
  {
    const uint4* qp = (const uint4*)qkf;
    #pragma unroll
    for (int k = 0; k < 8; ++k) qkg[k] = qp[k*64 + lane];
  }

  // loader mapping: unit e = u*256+tid -> (cp = e/14, p = e%14); rows 2p,2p+1; c = 2cp,2cp+1
  int goff[7], w0[7], w1[7];
  #pragma unroll
  for (int u = 0; u < 7; ++u) {
    const int e = u*256 + tid;
    const int cp = e / 14, p = e - cp*14;
    const int lr = p / 7, j = p - lr*7;
    goff[u] = (2*cp)*HW_IMG + lr*224 + 2*j;
    const int pc = cp + 4*(p & 7);
    w0[u] = (2*p)*160 + pc;
    w1[u] = (2*p+1)*160 + pc;
  }

  float2 va[7], vb[7];
  #pragma unroll
  for (int u = 0; u < 7; ++u) {
    va[u] = *(const float2*)(xb + goff[u]);
    vb[u] = *(const float2*)(xb + goff[u] + HW_IMG);
  }

  // score-phase addressing (waves 0,1): A-frag row = wid*16 + (lane&15)
  const int arow = wid*16 + (lane & 15);
  const int abase = arow*640 + (lane>>4)*16 + ((arow>>1)&7)*16;
  const int hcol = lane & 15;

  // pool-phase addressing: lane -> (c-oct o, row-parity half); heads 2*wid, 2*wid+1
  const int o = lane & 31, half = lane >> 5;
  const int pbase = o*16 + half*640;

  float m = -INFINITY, d = 0.f;
  float a0[8] = {0,0,0,0,0,0,0,0}, a1[8] = {0,0,0,0,0,0,0,0};

  #pragma unroll 1
  for (int t = 0; t < 7; ++t) {
    __syncthreads();                       // pool(t-1) finished reading Xs
    #pragma unroll
    for (int u = 0; u < 7; ++u) {
      ((unsigned*)Xs)[w0[u]] = bf16rn(va[u].x) | (bf16rn(vb[u].x) << 16);
      ((unsigned*)Xs)[w1[u]] = bf16rn(va[u].y) | (bf16rn(vb[u].y) << 16);
    }
    __syncthreads();                       // Xs(t) visible
    if (t < 6) {                           // prefetch t+1 into registers
      const float* xt = xb + (t+1)*448;
      #pragma unroll
      for (int u = 0; u < 7; ++u) {
        va[u] = *(const float2*)(xt + goff[u]);
        vb[u] = *(const float2*)(xt + goff[u] + HW_IMG);
      }
    }
    float s0 = 0.f, s1 = 0.f, s2 = 0.f, s3 = 0.f;
    if (wid < 2) {
      f32x4 sc = {0.f, 0.f, 0.f, 0.f};
      #pragma unroll
      for (int k = 0; k < 8; ++k) {
        U4B8 a; a.u = *(const uint4*)((const char*)Xs + abase + k*64);
        U4B8 bq; bq.u = qkg[k];
        sc = __builtin_amdgcn_mfma_f32_16x16x32_bf16(a.b, bq.b, sc, 0, 0, 0);
      }
      const bool pad = (wid == 1) && ((lane>>4) == 3);   // rows 28..31
      s0 = pad ? -INFINITY : sc[0];
      s1 = pad ? -INFINITY : sc[1];
      s2 = pad ? -INFINITY : sc[2];
      s3 = pad ? -INFINITY : sc[3];
      float mx = fmaxf(fmaxf(s0, s1), fmaxf(s2, s3));
      mx = fmaxf(mx, __shfl_xor(mx, 16));
      mx = fmaxf(mx, __shfl_xor(mx, 32));
      if (lane < 16) Ms[wid*16 + lane] = mx;
    }
    __syncthreads();                       // Ms ready
    if (wid < 2) {
      const float tm = fmaxf(Ms[hcol], Ms[16 + hcol]);
      const float mn = fmaxf(m, tm);
      const float scl = __expf(m - mn);
      m = mn;
      s0 = __expf(s0 - mn); s1 = __expf(s1 - mn);
      s2 = __expf(s2 - mn); s3 = __expf(s3 - mn);
      float ts = s0 + s1 + s2 + s3;
      ts += __shfl_xor(ts, 16); ts += __shfl_xor(ts, 32);
      if (lane < 16) Ss[wid*16 + lane] = ts;
      if (wid == 0 && lane < 8) SCs[lane] = scl;
      const int rbase = wid*16 + (lane>>4)*4;
      if (hcol < 8 && rbase < 28) {
        Wl[(rbase+0)*8 + hcol] = s0;
        Wl[(rbase+1)*8 + hcol] = s1;
        Wl[(rbase+2)*8 + hcol] = s2;
        Wl[(rbase+3)*8 + hcol] = s3;
      }
      d *= scl;
    }
    __syncthreads();                       // Wl/SCs ready
    if (wid < 2) d += Ss[hcol] + Ss[16 + hcol];
    // ---- pooling: heads (2*wid, 2*wid+1), c = 8o..8o+7, rows 2i+half ----
    {
      const float sa = SCs[2*wid], sb = SCs[2*wid + 1];
      #pragma unroll
      for (int nn = 0; nn < 8; ++nn) { a0[nn] *= sa; a1[nn] *= sb; }
      #pragma unroll
      for (int i = 0; i < 14; ++i) {
        const int r = 2*i + half;
        const uint4 xv = *(const uint4*)((const char*)Xs + pbase + i*1280 + (i&7)*16);
        const float2 w2 = *(const float2*)&Wl[r*8 + 2*wid];
        #pragma unroll
        for (int nn = 0; nn < 4; ++nn) {
          const unsigned uu = ((const unsigned*)&xv)[nn];
          const float xl = __uint_as_float(uu << 16);
          const float xh = __uint_as_float(uu & 0xffff0000u);
          a0[2*nn]   += w2.x * xl; a0[2*nn+1] += w2.x * xh;
          a1[2*nn]   += w2.y * xl; a1[2*nn+1] += w2.y * xh;
        }
      }
    }
  }

  if (wid == 0 && lane < 8) Ds[lane] = d;
  __syncthreads();
  {
    #pragma unroll
    for (int nn = 0; nn < 8; ++nn) {
      a0[nn] += __shfl_xor(a0[nn], 32);
      a1[nn] += __shfl_xor(a1[nn], 32);
    }
    if (half == 0) {
      const float i0 = 1.f / Ds[2*wid], i1 = 1.f / Ds[2*wid + 1];
      #pragma unroll
      for (int nn = 0; nn < 8; ++nn) { a0[nn] *= i0; a1[nn] *= i1; }
      f32x4 t0 = {a0[0], a0[1], a0[2], a0[3]};
      f32x4 t1 = {a0[4], a0[5], a0[6], a0[7]};
      f32x4 t2 = {a1[0], a1[1], a1[2], a1[3]};
      f32x4 t3 = {a1[4], a1[5], a1[6], a1[7]};
      *(f32x4*)&Xs[(2*wid)*256 + 8*o]       = t0;
      *(f32x4*)&Xs[(2*wid)*256 + 8*o + 4]   = t1;
      *(f32x4*)&Xs[(2*wid+1)*256 + 8*o]     = t2;
      *(f32x4*)&Xs[(2*wid+1)*256 + 8*o + 4] = t3;
    }
  }
  __syncthreads();
  {  // ctx[c'] = bv[c'] + sum_c wvT[c][c'] * pooled[h(c')][c]
    const int h2 = tid >> 5;
    float a = in_b[512 + tid];
    #pragma unroll 8
    for (int c = 0; c < 256; ++c) a += wvT[c*256 + tid] * Xs[h2*256 + c];
    Xs[2048 + tid] = a;
  }
  __syncthreads();
  {  // out[o'] = cb[o'] + sum_k cwT[k][o'] * ctx[k]
    float oo = cb[tid];
    #pragma unroll 8
    for (int k = 0; k < 256; ++k) oo += cwT[k*256 + tid] * Xs[2048 + k];
    out[(((size_t)b*256 + tid)*16 + pi)*16 + pj] = oo;
  }
}

extern "C" void kernel_launch(void* const* d_in, const int* in_sizes, int n_in,
                              void* d_out, int out_size, void* d_ws, size_t ws_size,
                              hipStream_t stream) {
  const float* X    = (const float*)d_in[0];
  const float* q    = (const float*)d_in[1];
  const float* in_w = (const float*)d_in[2];
  const float* in_b = (const float*)d_in[3];
  const float* aw   = (const float*)d_in[4];
  const float* aob  = (const float*)d_in[5];
  const float* ow   = (const float*)d_in[6];
  const float* ob   = (const float*)d_in[7];
  float* out = (float*)d_out;

  float* wsf = (float*)d_ws;
  float* qh   = wsf;                        // 256
  float* cb   = wsf + 256;                  // 256
  unsigned short* qkf = (unsigned short*)(wsf + 512);  // 8KB (2048 floats)
  float* wvT  = wsf + 4096;                 // 65536
  float* cwT  = wsf + 4096 + 65536;         // 65536

  hipLaunchKernelGGL(prep1_kernel, dim3(256),  dim3(256), 0, stream,
                     q, in_w, in_b, ow, aob, ob, qh, cb);
  hipLaunchKernelGGL(prep2_kernel, dim3(8),    dim3(64),  0, stream,
                     qh, in_w, qkf);
  hipLaunchKernelGGL(prep3_kernel, dim3(256),  dim3(256), 0, stream,
                     in_w, aw, ow, wvT, cwT);
  hipLaunchKernelGGL(attnpool_main, dim3(2048), dim3(256), 0, stream,
                     X, in_b, qkf, wvT, cwT, cb, out);
}

// Round 4
// 236.057 us; speedup vs baseline: 2.3397x; 1.7671x over previous
//
#include <hip/hip_runtime.h>

#define HW_IMG (224*224)
#define SCALE 0.17677669529663687f   // 1/sqrt(32)

typedef short bf16x8 __attribute__((ext_vector_type(8)));
typedef float f32x4 __attribute__((ext_vector_type(4)));
union U4B8 { uint4 u; bf16x8 b; };

__device__ __forceinline__ unsigned bf16rn(float f) {
  unsigned u = __float_as_uint(f);
  return (u + 0x7fffu + ((u >> 16) & 1u)) >> 16;
}

// ---- prep1: qh[r] = in_b[r] + query.in_w[r,:]; cb[r] = out_b[r] + out_w[r,:].aob ----
__global__ void prep1_kernel(const float* __restrict__ query,
                             const float* __restrict__ in_w,
                             const float* __restrict__ in_b,
                             const float* __restrict__ out_w,
                             const float* __restrict__ aob,
                             const float* __restrict__ out_b,
                             float* __restrict__ qh,
                             float* __restrict__ cb) {
  const int r = blockIdx.x, tid = threadIdx.x;
  float p1 = query[tid] * in_w[r*256 + tid];
  float p2 = aob[tid]   * out_w[r*256 + tid];
  #pragma unroll
  for (int o = 32; o; o >>= 1) { p1 += __shfl_xor(p1, o); p2 += __shfl_xor(p2, o); }
  __shared__ float t1[4], t2[4];
  if ((tid & 63) == 0) { t1[tid>>6] = p1; t2[tid>>6] = p2; }
  __syncthreads();
  if (tid == 0) qh[r] = in_b[r] + t1[0]+t1[1]+t1[2]+t1[3];
  if (tid == 1) cb[r] = out_b[r] + t2[0]+t2[1]+t2[2]+t2[3];
}

// ---- prep2: qk bf16 B-fragments for mfma_f32_16x16x32_bf16 ----
// frag[k][lane]: 8 bf16 = qk[c = 32k + (lane>>4)*8 + j][h = lane&15], h>=8 -> 0
__global__ void prep2_kernel(const float* __restrict__ qh,
                             const float* __restrict__ in_w,
                             unsigned short* __restrict__ qkf) {
  const int k = blockIdx.x;     // 0..7
  const int L = threadIdx.x;    // 0..63
  const int h = L & 15, q = L >> 4;
  unsigned short o[8];
  #pragma unroll
  for (int j = 0; j < 8; ++j) {
    float s = 0.f;
    if (h < 8) {
      const int c = k*32 + q*8 + j;
      #pragma unroll
      for (int dd = 0; dd < 32; ++dd)
        s += qh[h*32 + dd] * in_w[(256 + h*32 + dd)*256 + c];
      s *= SCALE;
    }
    o[j] = (unsigned short)bf16rn(s);
  }
  ushort4* dst = (ushort4*)(qkf + (size_t)(k*64 + L)*8);
  dst[0] = make_ushort4(o[0],o[1],o[2],o[3]);
  dst[1] = make_ushort4(o[4],o[5],o[6],o[7]);
}

// ---- prep3: wvT and (out_w @ attn_out_w)^T ----
__global__ void prep3_kernel(const float* __restrict__ in_w,
                             const float* __restrict__ aw,
                             const float* __restrict__ out_w,
                             float* __restrict__ wvT,
                             float* __restrict__ cwT) {
  const int o = blockIdx.x, t = threadIdx.x;
  wvT[t*256 + o] = in_w[(512 + o)*256 + t];
  float a = 0.f;
  #pragma unroll 4
  for (int k = 0; k < 256; ++k) a += out_w[o*256 + k] * aw[k*256 + t];
  cwT[t*256 + o] = a;
}

// ---- out transpose: pout[b][pos][c] -> out[b][c][pos], both sides coalesced ----
__global__ void transpose_out(const float* __restrict__ pout, float* __restrict__ out) {
  __shared__ float T[64*65];
  const int b  = blockIdx.x;    // image
  const int pc = blockIdx.y;    // pos chunk
  const int cc = blockIdx.z;    // chan chunk
  const int tid = threadIdx.x;
  const int lc = tid & 63, lr = tid >> 6;
  #pragma unroll
  for (int i = 0; i < 16; ++i) {
    const int p = i*4 + lr;
    T[p*65 + lc] = pout[((size_t)b*256 + pc*64 + p)*256 + cc*64 + lc];
  }
  __syncthreads();
  #pragma unroll
  for (int i = 0; i < 16; ++i) {
    const int c = i*4 + lr;
    out[((size_t)b*256 + cc*64 + c)*256 + pc*64 + lc] = T[lc*65 + c];
  }
}

// ---- main: one block per patch; bf16 LDS tile; MFMA scores; VALU pooling ----
__global__ __launch_bounds__(256)
__attribute__((amdgpu_waves_per_eu(2, 8)))
void attnpool_main(
    const float* __restrict__ X,
    const float* __restrict__ in_b,
    const unsigned short* __restrict__ qkf,
    const float* __restrict__ wvT,
    const float* __restrict__ cwT,
    const float* __restrict__ cb,
    float* __restrict__ pout,
    float* __restrict__ out) {
  // bf16 tile: element (r, c) -> u32 word r*160 + (c>>1) + 4*((r>>1)&7), lo=even c
  __shared__ float Xs[32*160];        // 20.5 KB (rows 28..31 zeroed pad)
  __shared__ uint4 QKs[8][64];        // qk B-fragments [kstep][lane], 8 KB
  __shared__ float Wl[28*8];          // tile attn weights (unnormalized) [l][h]
  __shared__ float Ms[32], Ss[32];    // per-wave max / sum staging [wid][hcol]
  __shared__ float SCs[8], Ds[8];     // per-tile rescale / final denom per head

  const int tid = threadIdx.x;
  const int wid = tid >> 6;
  const int lane = tid & 63;
  const int bid = blockIdx.x;
  const int n = (bid & 7) * 256 + (bid >> 3);   // XCD swizzle (2048%8==0)
  const int b = n >> 8, rem = n & 255, pi = rem >> 4, pj = rem & 15;
  const float* __restrict__ xb = X + (size_t)b*256*HW_IMG + pi*14*224 + pj*14;

  for (int z = tid; z < 640; z += 256) Xs[28*160 + z] = 0.f;  // zero pad rows

  // stage qk fragments into LDS (coalesced; visible after first tile sync)
  {
    const uint4* qp = (const uint4*)qkf;
    ((uint4*)QKs)[tid]       = qp[tid];
    ((uint4*)QKs)[256 + tid] = qp[256 + tid];
  }

  // loader mapping: unit e = u*256+tid -> (cp = e/14, p = e%14); rows 2p,2p+1; c = 2cp,2cp+1
  int goff[7], w0[7];
  #pragma unroll
  for (int u = 0; u < 7; ++u) {
    const int e = u*256 + tid;
    const int cp = e / 14, p = e - cp*14;
    const int lr = p / 7, j = p - lr*7;
    goff[u] = (2*cp)*HW_IMG + lr*224 + 2*j;
    w0[u] = (2*p)*160 + cp + 4*(p & 7);
  }

  float2 va[7], vb[7];
  #pragma unroll
  for (int u = 0; u < 7; ++u) {
    va[u] = *(const float2*)(xb + goff[u]);
    vb[u] = *(const float2*)(xb + goff[u] + HW_IMG);
  }

  // score-phase addressing (waves 0,1): A-frag row = wid*16 + (lane&15)
  const int arow = wid*16 + (lane & 15);
  const int abase = arow*640 + (lane>>4)*16 + ((arow>>1)&7)*16;
  const int hcol = lane & 15;

  // pool-phase addressing: lane -> (c-oct o, row-parity half); heads 2*wid, 2*wid+1
  const int o = lane & 31, half = lane >> 5;
  const int pbase = o*16 + half*640;

  float m = -INFINITY, d = 0.f;
  float a0[8] = {0,0,0,0,0,0,0,0}, a1[8] = {0,0,0,0,0,0,0,0};

  #pragma unroll 1
  for (int t = 0; t < 7; ++t) {
    __syncthreads();                       // pool(t-1) finished reading Xs
    #pragma unroll
    for (int u = 0; u < 7; ++u) {
      ((unsigned*)Xs)[w0[u]]       = bf16rn(va[u].x) | (bf16rn(vb[u].x) << 16);
      ((unsigned*)Xs)[w0[u] + 160] = bf16rn(va[u].y) | (bf16rn(vb[u].y) << 16);
    }
    __syncthreads();                       // Xs(t) [and QKs on t=0] visible
    if (t < 6) {                           // prefetch t+1 into registers
      const float* xt = xb + (t+1)*448;
      #pragma unroll
      for (int u = 0; u < 7; ++u) {
        va[u] = *(const float2*)(xt + goff[u]);
        vb[u] = *(const float2*)(xt + goff[u] + HW_IMG);
      }
    }
    float s0 = 0.f, s1 = 0.f, s2 = 0.f, s3 = 0.f;
    if (wid < 2) {
      f32x4 sc = {0.f, 0.f, 0.f, 0.f};
      #pragma unroll
      for (int k = 0; k < 8; ++k) {
        U4B8 a;  a.u  = *(const uint4*)((const char*)Xs + abase + k*64);
        U4B8 bq; bq.u = QKs[k][lane];
        sc = __builtin_amdgcn_mfma_f32_16x16x32_bf16(a.b, bq.b, sc, 0, 0, 0);
      }
      const bool pad = (wid == 1) && ((lane>>4) == 3);   // rows 28..31
      s0 = pad ? -INFINITY : sc[0];
      s1 = pad ? -INFINITY : sc[1];
      s2 = pad ? -INFINITY : sc[2];
      s3 = pad ? -INFINITY : sc[3];
      float mx = fmaxf(fmaxf(s0, s1), fmaxf(s2, s3));
      mx = fmaxf(mx, __shfl_xor(mx, 16));
      mx = fmaxf(mx, __shfl_xor(mx, 32));
      if (lane < 16) Ms[wid*16 + lane] = mx;
    }
    __syncthreads();                       // Ms ready
    if (wid < 2) {
      const float tm = fmaxf(Ms[hcol], Ms[16 + hcol]);
      const float mn = fmaxf(m, tm);
      const float scl = __expf(m - mn);
      m = mn;
      s0 = __expf(s0 - mn); s1 = __expf(s1 - mn);
      s2 = __expf(s2 - mn); s3 = __expf(s3 - mn);
      float ts = s0 + s1 + s2 + s3;
      ts += __shfl_xor(ts, 16); ts += __shfl_xor(ts, 32);
      if (lane < 16) Ss[wid*16 + lane] = ts;
      if (wid == 0 && lane < 8) SCs[lane] = scl;
      const int rbase = wid*16 + (lane>>4)*4;
      if (hcol < 8 && rbase < 28) {
        Wl[(rbase+0)*8 + hcol] = s0;
        Wl[(rbase+1)*8 + hcol] = s1;
        Wl[(rbase+2)*8 + hcol] = s2;
        Wl[(rbase+3)*8 + hcol] = s3;
      }
      d *= scl;
    }
    __syncthreads();                       // Wl/SCs ready
    if (wid < 2) d += Ss[hcol] + Ss[16 + hcol];
    // ---- pooling: heads (2*wid, 2*wid+1), c = 8o..8o+7, rows 2i+half ----
    {
      const float sa = SCs[2*wid], sb = SCs[2*wid + 1];
      #pragma unroll
      for (int nn = 0; nn < 8; ++nn) { a0[nn] *= sa; a1[nn] *= sb; }
      #pragma unroll
      for (int i = 0; i < 14; ++i) {
        const int r = 2*i + half;
        const uint4 xv = *(const uint4*)((const char*)Xs + pbase + i*1280 + (i&7)*16);
        const float2 w2 = *(const float2*)&Wl[r*8 + 2*wid];
        #pragma unroll
        for (int nn = 0; nn < 4; ++nn) {
          const unsigned uu = ((const unsigned*)&xv)[nn];
          const float xl = __uint_as_float(uu << 16);
          const float xh = __uint_as_float(uu & 0xffff0000u);
          a0[2*nn]   += w2.x * xl; a0[2*nn+1] += w2.x * xh;
          a1[2*nn]   += w2.y * xl; a1[2*nn+1] += w2.y * xh;
        }
      }
    }
  }

  if (wid == 0 && lane < 8) Ds[lane] = d;
  __syncthreads();
  {
    #pragma unroll
    for (int nn = 0; nn < 8; ++nn) {
      a0[nn] += __shfl_xor(a0[nn], 32);
      a1[nn] += __shfl_xor(a1[nn], 32);
    }
    if (half == 0) {
      const float i0 = 1.f / Ds[2*wid], i1 = 1.f / Ds[2*wid + 1];
      #pragma unroll
      for (int nn = 0; nn < 8; ++nn) { a0[nn] *= i0; a1[nn] *= i1; }
      f32x4 t0 = {a0[0], a0[1], a0[2], a0[3]};
      f32x4 t1 = {a0[4], a0[5], a0[6], a0[7]};
      f32x4 t2 = {a1[0], a1[1], a1[2], a1[3]};
      f32x4 t3 = {a1[4], a1[5], a1[6], a1[7]};
      *(f32x4*)&Xs[(2*wid)*256 + 8*o]       = t0;
      *(f32x4*)&Xs[(2*wid)*256 + 8*o + 4]   = t1;
      *(f32x4*)&Xs[(2*wid+1)*256 + 8*o]     = t2;
      *(f32x4*)&Xs[(2*wid+1)*256 + 8*o + 4] = t3;
    }
  }
  __syncthreads();
  {  // ctx[c'] = bv[c'] + sum_c wvT[c][c'] * pooled[h(c')][c]
    const int h2 = tid >> 5;
    float a = in_b[512 + tid];
    #pragma unroll 8
    for (int c = 0; c < 256; ++c) a += wvT[c*256 + tid] * Xs[h2*256 + c];
    Xs[2048 + tid] = a;
  }
  __syncthreads();
  {  // out[o'] = cb[o'] + sum_k cwT[k][o'] * ctx[k]
    float oo = cb[tid];
    #pragma unroll 8
    for (int k = 0; k < 256; ++k) oo += cwT[k*256 + tid] * Xs[2048 + k];
    if (pout) pout[(size_t)n*256 + tid] = oo;                       // coalesced
    else out[(((size_t)b*256 + tid)*16 + pi)*16 + pj] = oo;         // fallback
  }
}

extern "C" void kernel_launch(void* const* d_in, const int* in_sizes, int n_in,
                              void* d_out, int out_size, void* d_ws, size_t ws_size,
                              hipStream_t stream) {
  const float* X    = (const float*)d_in[0];
  const float* q    = (const float*)d_in[1];
  const float* in_w = (const float*)d_in[2];
  const float* in_b = (const float*)d_in[3];
  const float* aw   = (const float*)d_in[4];
  const float* aob  = (const float*)d_in[5];
  const float* ow   = (const float*)d_in[6];
  const float* ob   = (const float*)d_in[7];
  float* out = (float*)d_out;

  float* wsf = (float*)d_ws;
  float* qh   = wsf;                        // 256
  float* cb   = wsf + 256;                  // 256
  unsigned short* qkf = (unsigned short*)(wsf + 512);  // 8KB
  float* wvT  = wsf + 4096;                 // 65536
  float* cwT  = wsf + 4096 + 65536;         // 65536
  const size_t need = (size_t)(4096 + 2*65536 + 2048*256) * sizeof(float);
  float* pout = (ws_size >= need) ? (wsf + 4096 + 2*65536) : nullptr;  // 2 MB

  hipLaunchKernelGGL(prep1_kernel, dim3(256),  dim3(256), 0, stream,
                     q, in_w, in_b, ow, aob, ob, qh, cb);
  hipLaunchKernelGGL(prep2_kernel, dim3(8),    dim3(64),  0, stream,
                     qh, in_w, qkf);
  hipLaunchKernelGGL(prep3_kernel, dim3(256),  dim3(256), 0, stream,
                     in_w, aw, ow, wvT, cwT);
  hipLaunchKernelGGL(attnpool_main, dim3(2048), dim3(256), 0, stream,
                     X, in_b, qkf, wvT, cwT, cb, pout, out);
  if (pout)
    hipLaunchKernelGGL(transpose_out, dim3(8, 4, 4), dim3(256), 0, stream,
                       pout, out);
}